// Round 5
// baseline (195.220 us; speedup 1.0000x reference)
//
#include <hip/hip_runtime.h>
#include <hip/hip_bf16.h>

#define N_ROWS 8192
#define D_DIM  256

// loss_i = log(sum_{j != i} exp(<x_i,y_j>/T)) - <x_i,y_i>/T ; out = mean_i loss_i
// fp8 e4m3 inputs (scale 64), PLAIN row-major; acc = 4096*<x,y> via MX-scaled
// MFMA 16x16x128 with unit E8M0 scales (exact fp8 dot); 1/4096 in constants.
static constexpr float kQuantScale = 64.0f;
static constexpr float kScaleAcc = 20.609929155556627f / 4096.0f;  // (1/T)*log2(e)/4096
static constexpr float kInvTAcc  = 14.285714285714286f / 4096.0f;  // (1/T)/4096

typedef float f32x4 __attribute__((ext_vector_type(4)));
typedef int   i32x4 __attribute__((ext_vector_type(4)));
typedef int   i32x8 __attribute__((ext_vector_type(8)));

#define WAITV(n) asm volatile("s_waitcnt vmcnt(" #n ")" ::: "memory")

// async 16B global->LDS: LDS dest = wave-uniform base + lane*16
__device__ __forceinline__ void gl_lds16(const void* g, void* l) {
  __builtin_amdgcn_global_load_lds(
      (const __attribute__((address_space(1))) void*)g,
      (__attribute__((address_space(3))) void*)l, 16, 0, 0);
}

// ---------------- fp32 -> fp8 e4m3 pre-convert (plain layout) + ws init --------
__global__ __launch_bounds__(256)
void cvt_fp8_kernel(const float* __restrict__ x, const float* __restrict__ y,
                    unsigned char* __restrict__ xq, unsigned char* __restrict__ yq,
                    float* __restrict__ rowsum, unsigned int* __restrict__ done,
                    float* __restrict__ out) {
  if (blockIdx.x == 0) {
    for (int i = threadIdx.x; i < N_ROWS; i += 256) rowsum[i] = 0.f;
    if (threadIdx.x < 32) done[threadIdx.x] = 0u;
    if (threadIdx.x == 32) out[0] = 0.f;
  }
  const int per_mat = N_ROWS * D_DIM / 8;  // 8 elements per thread
  int idx = blockIdx.x * blockDim.x + threadIdx.x;
  const float* src = x;
  unsigned char* dst = xq;
  int i = idx;
  if (idx >= per_mat) { src = y; dst = yq; i = idx - per_mat; }
  float4 a = ((const float4*)src)[2 * (size_t)i];
  float4 b = ((const float4*)src)[2 * (size_t)i + 1];
  int v0 = 0, v1 = 0;
  v0 = __builtin_amdgcn_cvt_pk_fp8_f32(a.x * kQuantScale, a.y * kQuantScale, v0, false);
  v0 = __builtin_amdgcn_cvt_pk_fp8_f32(a.z * kQuantScale, a.w * kQuantScale, v0, true);
  v1 = __builtin_amdgcn_cvt_pk_fp8_f32(b.x * kQuantScale, b.y * kQuantScale, v1, false);
  v1 = __builtin_amdgcn_cvt_pk_fp8_f32(b.z * kQuantScale, b.w * kQuantScale, v1, true);
  *(int2*)(dst + (size_t)i * 8) = make_int2(v0, v1);   // plain row-major
}

// ---------------- persistent fused GEMM(MX-fp8) + exp + row-sum + finalize -----
// R22 REDESIGN (T3+T4+T5 from the CDNA4 guide, m201 phase template):
// R17 counters (MfmaUtil 13, VALUBusy 19, LDS pipe ~15%, conflicts 0, HBM 3%)
// = the measured "2-phase stall" signature (m233: ~72% structural overhead).
// R18/R19 micro-placement and R21 occupancy changes were all ~neutral; the
// lever is the barrier/waitcnt STRUCTURE:
//  - 256 blocks (1/CU), 512 thr, block = 256 rows x 1024 cols (gj group).
//  - Y in 16 tiles of 64 cols, QUAD-buffered (Xs 64K + Ys 4x16K = 128K LDS).
//  - Per tile, 2 phases (one per MX k-block of 128):
//      {ds_read frags ; [kb0: issue stage(tt+3)] ; sched_barrier ;
//       s_barrier ; setprio(1) ; 8 MFMA ; setprio(0) ; s_barrier}
//  - COUNTED vmcnt: one s_waitcnt vmcnt(4) per tile (leaves the 2 future
//    tiles' 4 loads in flight across barriers); vmcnt(2)/(0) only in the
//    drain tail; raw s_barrier everywhere in the loop (no __syncthreads
//    vmcnt(0) drain). 3-deep prefetch tolerates L2-evict/fill-contention.
//  - Epilogue (exp2+psum+diag+acc-zero, register-only) runs at tile-top
//    after the closing barrier, BEFORE next reads (avoids R19's trap).
// WAR safety: buf written at tile tt was last read at tile tt-1; those
// ds_reads retired before tt-1's MFMAs, which precede the barrier the write
// follows. Counted-vmcnt safety: vmcnt retires oldest-first, so tile tt+1's
// loads (always oldest) are covered by any wait to <=4; diag atomics only
// make the wait stricter. Single-ticket finalize (R15-proven, ticket==255).
__global__ __launch_bounds__(512, 1)
void infonce_gemm(const unsigned char* __restrict__ X,
                  const unsigned char* __restrict__ Y,
                  float* __restrict__ rowsum, float* __restrict__ diag,
                  unsigned int* __restrict__ done, float* __restrict__ out) {
  __shared__ unsigned char Xs[256 * 256];      // 64 KB, X-block full-K
  __shared__ unsigned char Ys[4][64 * 256];    // 4 x 16 KB, Y tile quad-buf
  __shared__ unsigned int ticket_s;

  const int b  = blockIdx.x;        // 0..255
  const int bi = b >> 3;            // 0..31: X-row-block (256 rows)
  const int gj = b & 7;             // col-group: 1024 cols = 16 tiles of 64

  const int t    = threadIdx.x;
  const int lane = t & 63;
  const int wave = t >> 6;        // 0..7
  const int wm   = wave >> 1;     // 0..3  (64-row band)
  const int wn   = wave & 1;      // 0..1  (32-col half of 64-col tile)
  const int quad = lane >> 4;     // 0..3
  const int l15  = lane & 15;

  const unsigned char* Xblk = X + (size_t)(bi * 256) * D_DIM;

  // stage one 64-col Y tile (1024 slots of 16B, 2 per thread) into buf
  auto stageY = [&](int tile, int buf) {
#pragma unroll
    for (int it = 0; it < 2; ++it) {
      const int c0  = (it * 8 + wave) * 64;
      const int s   = c0 + lane;
      const int row = s >> 4;                 // 0..63
      const int cg  = (s & 15) ^ (row & 15);  // inverse swizzle on global side
      gl_lds16(Y + (size_t)(gj * 1024 + tile * 64 + row) * D_DIM + cg * 16,
               &Ys[buf][c0 * 16]);
    }
  };

  // ---- prologue: stage X (4096 slots, 8/thread) + Y tiles 0,1,2 ----
#pragma unroll
  for (int it = 0; it < 8; ++it) {
    const int c0  = (it * 8 + wave) * 64;
    const int s   = c0 + lane;
    const int row = s >> 4;                 // 0..255
    const int cg  = (s & 15) ^ (row & 15);
    gl_lds16(Xblk + (size_t)row * D_DIM + cg * 16, &Xs[c0 * 16]);
  }
  stageY(0, 0);
  stageY(1, 1);
  stageY(2, 2);
  WAITV(4);                            // X + Y0 landed; Y1,Y2 (4 loads) in flight
  __builtin_amdgcn_s_barrier();

  f32x4 acc[4][2];
#pragma unroll
  for (int a = 0; a < 4; ++a)
#pragma unroll
    for (int c = 0; c < 2; ++c) acc[a][c] = (f32x4){0.f, 0.f, 0.f, 0.f};

  float psum[4][4];
#pragma unroll
  for (int a = 0; a < 4; ++a)
#pragma unroll
    for (int c = 0; c < 4; ++c) psum[a][c] = 0.f;

  // register-only epilogue for tile rt: exp2+psum, diagonal, acc re-zero.
  auto do_epilogue = [&](const int rt) {
#pragma unroll
    for (int mt = 0; mt < 4; ++mt) {
#pragma unroll
      for (int rr = 0; rr < 4; ++rr) {
        psum[mt][rr] += __builtin_amdgcn_exp2f(acc[mt][0][rr] * kScaleAcc)
                      + __builtin_amdgcn_exp2f(acc[mt][1][rr] * kScaleAcc);
      }
    }
    // diagonal: cols of tile rt are global (gj*16+rt)*64; they hit this
    // block's rows iff h = gj*16+rt-4*bi is in [0,4), on wave band wm==h.
    // Then row-local mt*16+quad*4+rr == col-local wn*32+nt*16+l15
    //  => mt = wn*2+nt and l15 == quad*4+rr.
    const int h = gj * 16 + rt - 4 * bi;
    if (h >= 0 && h < 4 && wm == h) {
#pragma unroll
      for (int nt = 0; nt < 2; ++nt)
#pragma unroll
        for (int rr = 0; rr < 4; ++rr)
          if (l15 == quad * 4 + rr)
            atomicExch(&diag[bi * 256 + wm * 64 + (wn * 2 + nt) * 16 + l15],
                       acc[wn * 2 + nt][nt][rr]);
    }
#pragma unroll
    for (int a = 0; a < 4; ++a)
#pragma unroll
      for (int c = 0; c < 2; ++c) acc[a][c] = (f32x4){0.f, 0.f, 0.f, 0.f};
  };

#pragma unroll
  for (int tt = 0; tt < 16; ++tt) {
    const int buf = tt & 3;

    if (tt > 0) do_epilogue(tt - 1);   // after prev closing barrier, before reads

#pragma unroll
    for (int kb = 0; kb < 2; ++kb) {
      i32x8 a8[4], b8[2];
#pragma unroll
      for (int mt = 0; mt < 4; ++mt) {
        const int row = wm * 64 + mt * 16 + l15;
        const int p0  = (kb * 8 + quad * 2) ^ (row & 15);
        i32x4 lo = *(const i32x4*)(&Xs[row * 256 + p0 * 16]);
        i32x4 hi = *(const i32x4*)(&Xs[row * 256 + (p0 ^ 1) * 16]);
        a8[mt] = __builtin_shufflevector(lo, hi, 0, 1, 2, 3, 4, 5, 6, 7);
      }
#pragma unroll
      for (int nt = 0; nt < 2; ++nt) {
        const int row = wn * 32 + nt * 16 + l15;
        const int p0  = (kb * 8 + quad * 2) ^ (row & 15);
        i32x4 lo = *(const i32x4*)(&Ys[buf][row * 256 + p0 * 16]);
        i32x4 hi = *(const i32x4*)(&Ys[buf][row * 256 + (p0 ^ 1) * 16]);
        b8[nt] = __builtin_shufflevector(lo, hi, 0, 1, 2, 3, 4, 5, 6, 7);
      }

      if (kb == 0 && tt + 3 < 16) stageY(tt + 3, (tt + 3) & 3);

      __builtin_amdgcn_sched_barrier(0);   // pin reads+stage before the barrier
      __builtin_amdgcn_s_barrier();

      __builtin_amdgcn_s_setprio(1);
#pragma unroll
      for (int mt = 0; mt < 4; ++mt)
#pragma unroll
        for (int nt = 0; nt < 2; ++nt)
          acc[mt][nt] = __builtin_amdgcn_mfma_scale_f32_16x16x128_f8f6f4(
              a8[mt], b8[nt], acc[mt][nt],
              0, 0,                    // cbsz=fp8 e4m3, blgp=fp8 e4m3
              0, 0x7F7F7F7F,           // A scales = 1.0 (E8M0 127)
              0, 0x7F7F7F7F);          // B scales = 1.0
      __builtin_amdgcn_s_setprio(0);

      if (kb == 0) {
        __builtin_amdgcn_s_barrier();
      } else {
        // counted drain: ensure tile tt+1 landed; keep future tiles in flight
        if (tt <= 12)      { WAITV(4); }
        else if (tt == 13) { WAITV(2); }
        else if (tt == 14) { WAITV(0); }
        if (tt < 15) __builtin_amdgcn_s_barrier();
      }
    }
  }

  do_epilogue(15);

  // ---- one reduce + flush per block (8 shfl-chains + 8 atomics per wave) ----
  {
    const int gi_base = bi * 256 + wm * 64;
#pragma unroll
    for (int mt = 0; mt < 4; ++mt) {
#pragma unroll
      for (int rr = 0; rr < 4; ++rr) {
        float v = psum[mt][rr];
        v += __shfl_xor(v, 1);
        v += __shfl_xor(v, 2);
        v += __shfl_xor(v, 4);
        v += __shfl_xor(v, 8);
        if (l15 == 0)
          atomicAdd(&rowsum[gi_base + mt * 16 + quad * 4 + rr], v);
      }
    }
  }

  // ---- last-block finalize (single fence, single ticket — R15-proven) ----
  __syncthreads();                       // drains this block's atomics (vmcnt)
  if (t == 0) ticket_s = atomicAdd(&done[0], 1u);
  __syncthreads();
  if (ticket_s == 255u) {
    __threadfence();                     // one acquire, one block only
    float local = 0.f;
    for (int i = t; i < N_ROWS; i += 512) {
      const float rs = atomicAdd(&rowsum[i], 0.0f);   // device-coherent read
      const float d  = atomicAdd(&diag[i], 0.0f);
      local += __logf(rs - __builtin_amdgcn_exp2f(d * kScaleAcc)) - d * kInvTAcc;
    }
    float* red = (float*)Xs;             // Xs dead after last round; reuse
    red[t] = local;
    __syncthreads();
    for (int s2 = 256; s2 > 0; s2 >>= 1) {
      if (t < s2) red[t] += red[t + s2];
      __syncthreads();
    }
    if (t == 0) out[0] = red[0] / (float)N_ROWS;
  }
}

extern "C" void kernel_launch(void* const* d_in, const int* in_sizes, int n_in,
                              void* d_out, int out_size, void* d_ws, size_t ws_size,
                              hipStream_t stream) {
  const float* x = (const float*)d_in[0];
  const float* y = (const float*)d_in[1];
  float* out = (float*)d_out;

  // ws layout: rowsum[N] f32 | diag[N] f32 | done[32] u32 (128 B) | xq | yq
  float* rowsum = (float*)d_ws;
  float* diag   = rowsum + N_ROWS;
  unsigned int* done = (unsigned int*)(diag + N_ROWS);
  unsigned char* xq = (unsigned char*)d_ws + 2 * N_ROWS * sizeof(float) + 128;
  unsigned char* yq = xq + (size_t)N_ROWS * D_DIM;

  int cvt_blocks = 2 * N_ROWS * D_DIM / 8 / 256;  // 2048
  cvt_fp8_kernel<<<cvt_blocks, 256, 0, stream>>>(x, y, xq, yq, rowsum, done, out);

  infonce_gemm<<<256, 512, 0, stream>>>(xq, yq, rowsum, diag, done, out);
}